// Round 5
// baseline (438.399 us; speedup 1.0000x reference)
//
#include <hip/hip_runtime.h>
#include <cstdint>

#define VOCAB_N 50000
#define EMB_N   16
#define HID_N   32
#define B_N     4096
#define T_N     500

typedef __attribute__((ext_vector_type(8))) short bf16x8;   // 8 bf16 (4 VGPRs)
typedef __attribute__((ext_vector_type(4))) float f32x4;    // MFMA acc

__device__ __forceinline__ float frcp(float x) { return __builtin_amdgcn_rcpf(x); }
__device__ __forceinline__ float sigm(float x) {
  return frcp(1.0f + exp2f(x * -1.4426950408889634f));
}
__device__ __forceinline__ float tanh_fast(float x) {
  return fmaf(-2.0f, frcp(1.0f + exp2f(x * 2.8853900817779268f)), 1.0f);
}

// truncation split: x = hi(bf16) + lo(bf16) + O(2^-24 x)
// packed return: bits[15:0] = hi, bits[31:16] = lo  (by-value, vector-element safe)
__device__ __forceinline__ unsigned bf16_split_pack(float x) {
  unsigned u  = __builtin_bit_cast(unsigned, x);
  float hif = __builtin_bit_cast(float, u & 0xFFFF0000u);
  float r   = x - hif;                       // exact
  unsigned lo = __builtin_bit_cast(unsigned, r) >> 16;
  return (u >> 16) | (lo << 16);
}

// ---------------------------------------------------------------------------
// proj[v][c][n] = bias[16n+c] + sum_e emb[v][e] * W[e][16n+c]   (c=0..15,n=0..7)
// flat index = v*128 + c*8 + n
// ---------------------------------------------------------------------------
__global__ void build_proj_mfma(const float* __restrict__ emb,
                                const float* __restrict__ W,
                                const float* __restrict__ bias,
                                float* __restrict__ proj) {
  __shared__ float Wl[EMB_N * 128];
  __shared__ float bl[128];
  const int tid = threadIdx.x;
  for (int i = tid; i < EMB_N * 128 / 4; i += 256)
    reinterpret_cast<float4*>(Wl)[i] = reinterpret_cast<const float4*>(W)[i];
  if (tid < 32)
    reinterpret_cast<float4*>(bl)[tid] = reinterpret_cast<const float4*>(bias)[tid];
  __syncthreads();

  const long long gid = (long long)blockIdx.x * 256 + tid;
  if (gid >= (long long)VOCAB_N * 128) return;
  const int v = (int)(gid >> 7);
  const int q = (int)(gid & 127);
  const int c = q >> 3, n = q & 7;
  const int col = n * 16 + c;

  const float4* ev = reinterpret_cast<const float4*>(emb + (size_t)v * EMB_N);
  float4 e0 = ev[0], e1 = ev[1], e2 = ev[2], e3 = ev[3];
  const float em[16] = {e0.x,e0.y,e0.z,e0.w, e1.x,e1.y,e1.z,e1.w,
                        e2.x,e2.y,e2.z,e2.w, e3.x,e3.y,e3.z,e3.w};
  float a = bl[col];
#pragma unroll
  for (int e = 0; e < EMB_N; ++e) a = fmaf(em[e], Wl[e * 128 + col], a);
  proj[gid] = a;
}

// ---------------------------------------------------------------------------
// MFMA scan: 1 wave (64 thr) per 4 batch rows, rows at tile-rows {0,4,8,12}.
// z-tile [16 x 128] per step via 24x mfma_f32_16x16x32_bf16 (hi/lo split).
// Gate instances: lane l handles (row 4*(l>>4), units l&15 and (l&15)+16),
// whose z values are exactly acc[n].x for n=0..7 (m89 C-layout:
// col=lane&15, row=(lane>>4)*4+reg).
// ---------------------------------------------------------------------------
#define SPLIT8(VAL, IDX)                                                      \
  { unsigned s_ = bf16_split_pack(VAL);                                       \
    Ah[IDX] = (short)s_; Al[IDX] = (short)(s_ >> 16); }

#define LSTM_MSTEP(TOKC, TOKP, XP0, XP1)                                      \
  {                                                                           \
    /* A-frag: lane reads h row (l&15), k = g*8..g*8+7 from LDS */            \
    float4 hv0 = *reinterpret_cast<const float4*>(&hl[c16][g8]);              \
    float4 hv1 = *reinterpret_cast<const float4*>(&hl[c16][g8 + 4]);          \
    bf16x8 Ah, Al;                                                            \
    SPLIT8(hv0.x, 0) SPLIT8(hv0.y, 1) SPLIT8(hv0.z, 2) SPLIT8(hv0.w, 3)      \
    SPLIT8(hv1.x, 4) SPLIT8(hv1.y, 5) SPLIT8(hv1.z, 6) SPLIT8(hv1.w, 7)      \
    f32x4 z0 = {(XP0).x, 0.f, 0.f, 0.f};                                      \
    f32x4 z1 = {(XP0).y, 0.f, 0.f, 0.f};                                      \
    f32x4 z2 = {(XP0).z, 0.f, 0.f, 0.f};                                      \
    f32x4 z3 = {(XP0).w, 0.f, 0.f, 0.f};                                      \
    f32x4 z4 = {(XP1).x, 0.f, 0.f, 0.f};                                      \
    f32x4 z5 = {(XP1).y, 0.f, 0.f, 0.f};                                      \
    f32x4 z6 = {(XP1).z, 0.f, 0.f, 0.f};                                      \
    f32x4 z7 = {(XP1).w, 0.f, 0.f, 0.f};                                      \
    z0 = __builtin_amdgcn_mfma_f32_16x16x32_bf16(Ah, Bh0, z0, 0, 0, 0);       \
    z1 = __builtin_amdgcn_mfma_f32_16x16x32_bf16(Ah, Bh1, z1, 0, 0, 0);       \
    z2 = __builtin_amdgcn_mfma_f32_16x16x32_bf16(Ah, Bh2, z2, 0, 0, 0);       \
    z3 = __builtin_amdgcn_mfma_f32_16x16x32_bf16(Ah, Bh3, z3, 0, 0, 0);       \
    z4 = __builtin_amdgcn_mfma_f32_16x16x32_bf16(Ah, Bh4, z4, 0, 0, 0);       \
    z5 = __builtin_amdgcn_mfma_f32_16x16x32_bf16(Ah, Bh5, z5, 0, 0, 0);       \
    z6 = __builtin_amdgcn_mfma_f32_16x16x32_bf16(Ah, Bh6, z6, 0, 0, 0);       \
    z7 = __builtin_amdgcn_mfma_f32_16x16x32_bf16(Ah, Bh7, z7, 0, 0, 0);       \
    z0 = __builtin_amdgcn_mfma_f32_16x16x32_bf16(Ah, Bl0, z0, 0, 0, 0);       \
    z1 = __builtin_amdgcn_mfma_f32_16x16x32_bf16(Ah, Bl1, z1, 0, 0, 0);       \
    z2 = __builtin_amdgcn_mfma_f32_16x16x32_bf16(Ah, Bl2, z2, 0, 0, 0);       \
    z3 = __builtin_amdgcn_mfma_f32_16x16x32_bf16(Ah, Bl3, z3, 0, 0, 0);       \
    z4 = __builtin_amdgcn_mfma_f32_16x16x32_bf16(Ah, Bl4, z4, 0, 0, 0);       \
    z5 = __builtin_amdgcn_mfma_f32_16x16x32_bf16(Ah, Bl5, z5, 0, 0, 0);       \
    z6 = __builtin_amdgcn_mfma_f32_16x16x32_bf16(Ah, Bl6, z6, 0, 0, 0);       \
    z7 = __builtin_amdgcn_mfma_f32_16x16x32_bf16(Ah, Bl7, z7, 0, 0, 0);       \
    z0 = __builtin_amdgcn_mfma_f32_16x16x32_bf16(Al, Bh0, z0, 0, 0, 0);       \
    z1 = __builtin_amdgcn_mfma_f32_16x16x32_bf16(Al, Bh1, z1, 0, 0, 0);       \
    z2 = __builtin_amdgcn_mfma_f32_16x16x32_bf16(Al, Bh2, z2, 0, 0, 0);       \
    z3 = __builtin_amdgcn_mfma_f32_16x16x32_bf16(Al, Bh3, z3, 0, 0, 0);       \
    z4 = __builtin_amdgcn_mfma_f32_16x16x32_bf16(Al, Bh4, z4, 0, 0, 0);       \
    z5 = __builtin_amdgcn_mfma_f32_16x16x32_bf16(Al, Bh5, z5, 0, 0, 0);       \
    z6 = __builtin_amdgcn_mfma_f32_16x16x32_bf16(Al, Bh6, z6, 0, 0, 0);       \
    z7 = __builtin_amdgcn_mfma_f32_16x16x32_bf16(Al, Bh7, z7, 0, 0, 0);       \
    /* prefetch x_proj for t+2 (per lane-group token) */                      \
    {                                                                         \
      const float4* xp_p = reinterpret_cast<const float4*>(                   \
          proj + ((size_t)(TOKP) << 7) + c16 * 8);                            \
      (XP0) = xp_p[0]; (XP1) = xp_p[1];                                       \
    }                                                                         \
    /* gates: instance0 = unit c16, instance1 = unit c16+16 */                \
    {                                                                         \
      float i0 = sigm(z0.x), f0 = sigm(z2.x);                                 \
      float g0 = tanh_fast(z4.x), o0 = sigm(z6.x);                            \
      float i1 = sigm(z1.x), f1 = sigm(z3.x);                                 \
      float g1 = tanh_fast(z5.x), o1 = sigm(z7.x);                            \
      float cn0 = fmaf(f0, c0, i0 * g0);                                      \
      float cn1 = fmaf(f1, c1, i1 * g1);                                      \
      float hn0 = o0 * tanh_fast(cn0);                                        \
      float hn1 = o1 * tanh_fast(cn1);                                        \
      bool m = (TOKC) != 0;                                                   \
      c0 = m ? cn0 : c0;  h0 = m ? hn0 : h0;                                  \
      c1 = m ? cn1 : c1;  h1 = m ? hn1 : h1;                                  \
      hl[myrow][c16]      = h0;                                               \
      hl[myrow][c16 + 16] = h1;                                               \
      asm volatile("" ::: "memory");   /* keep next ds_read after writes */   \
    }                                                                         \
  }

__global__ __launch_bounds__(64, 1)
void lstm_mfma_kernel(const int*   __restrict__ tokens,
                      const float* __restrict__ rec_kernel,  // [32][128] f32
                      const float* __restrict__ proj,        // [VOCAB][16][8]
                      float*       __restrict__ out) {
  __shared__ float hl[16][36];       // padded: stride 36 floats
  __shared__ int   tokl[4][512];     // 4 rows x (500 + pad)

  const int l   = threadIdx.x;       // 0..63
  const int g   = l >> 4;            // lane group 0..3
  const int c16 = l & 15;
  const int g8  = g * 8;
  const int myrow = 4 * g;           // tile-row of this lane's gate instances

  // ---- zero h state ----
  for (int i = l; i < 16 * 36; i += 64) (&hl[0][0])[i] = 0.0f;

  // ---- stage tokens: 4 rows x 500 ints contiguous ----
  {
    const int4* src = reinterpret_cast<const int4*>(tokens + (size_t)blockIdx.x * 4 * T_N);
    for (int i = l; i < T_N; i += 64) {      // 500 int4 = 2000 ints
      int4 v4 = src[i];
      int gi = 4 * i;
      int r  = gi / T_N;                     // 500 % 4 == 0: no straddle
      int cc = gi - r * T_N;
      *reinterpret_cast<int4*>(&tokl[r][cc]) = v4;
    }
    if (l < 48) { int r = l / 12, cc = T_N + (l % 12); tokl[r][cc] = 0; }
  }
  asm volatile("" ::: "memory");   // init writes complete before scan reads

  // ---- B-fragments of R (one-time): lane holds B[k=g*8+j][col=16n+c16] ----
  bf16x8 Bh0, Bh1, Bh2, Bh3, Bh4, Bh5, Bh6, Bh7;
  bf16x8 Bl0, Bl1, Bl2, Bl3, Bl4, Bl5, Bl6, Bl7;
#define BUILD_B(N, BH, BL)                                                    \
  {                                                                           \
    _Pragma("unroll")                                                         \
    for (int j = 0; j < 8; ++j) {                                             \
      float x = rec_kernel[(g8 + j) * 128 + (N) * 16 + c16];                  \
      unsigned s_ = bf16_split_pack(x);                                       \
      (BH)[j] = (short)s_; (BL)[j] = (short)(s_ >> 16);                       \
    }                                                                         \
  }
  BUILD_B(0, Bh0, Bl0) BUILD_B(1, Bh1, Bl1) BUILD_B(2, Bh2, Bl2)
  BUILD_B(3, Bh3, Bl3) BUILD_B(4, Bh4, Bl4) BUILD_B(5, Bh5, Bl5)
  BUILD_B(6, Bh6, Bl6) BUILD_B(7, Bh7, Bl7)
#undef BUILD_B

  float c0 = 0.f, c1 = 0.f, h0 = 0.f, h1 = 0.f;

  // ---- token pipeline (per lane-group) ----
  int tA = tokl[g][0], tB = tokl[g][1], tC = tokl[g][2], tD = tokl[g][3];

  float4 xpA0, xpA1, xpB0, xpB1;
  {
    const float4* p0 = reinterpret_cast<const float4*>(proj + ((size_t)tA << 7) + c16 * 8);
    xpA0 = p0[0]; xpA1 = p0[1];
    const float4* p1 = reinterpret_cast<const float4*>(proj + ((size_t)tB << 7) + c16 * 8);
    xpB0 = p1[0]; xpB1 = p1[1];
  }

#pragma unroll 1
  for (int t = 0; t < T_N; t += 2) {
    int2 tnew = *reinterpret_cast<const int2*>(&tokl[g][t + 4]);

    LSTM_MSTEP(tA, tC, xpA0, xpA1);   // step t,   prefetch t+2
    LSTM_MSTEP(tB, tD, xpB0, xpB1);   // step t+1, prefetch t+3

    tA = tC; tB = tD; tC = tnew.x; tD = tnew.y;
  }

  const size_t obase = ((size_t)blockIdx.x * 4 + g) * HID_N;
  out[obase + c16]      = h0;
  out[obase + c16 + 16] = h1;
}

// ---------------------------------------------------------------------------
// Fallback (no workspace): proven round-1 kernel (vector path, inline x_proj).
// ---------------------------------------------------------------------------
__global__ __launch_bounds__(256, 2)
void lstm_scan_fallback(const int*   __restrict__ tokens,
                        const float* __restrict__ rec_kernel,
                        const float* __restrict__ emb,
                        const float* __restrict__ W,
                        const float* __restrict__ bias,
                        float*       __restrict__ out) {
  __shared__ int   tokl[8][T_N];
  __shared__ float hbuf[8][HID_N];

  const int tid  = threadIdx.x;
  const int wv   = tid >> 6;
  const int lane = tid & 63;
  const int half = lane >> 5;
  const int j    = lane & 31;
  const int wrow = wv * 2 + half;
  const int row  = blockIdx.x * 8 + wrow;

  {
    const int4* src = reinterpret_cast<const int4*>(tokens + (size_t)blockIdx.x * 8 * T_N);
    int4* dst = reinterpret_cast<int4*>(&tokl[0][0]);
    for (int i = tid; i < 8 * T_N / 4; i += 256) dst[i] = src[i];
  }

  float wr[HID_N][4];
#pragma unroll
  for (int k = 0; k < HID_N; ++k)
#pragma unroll
    for (int gg2 = 0; gg2 < 4; ++gg2) wr[k][gg2] = rec_kernel[k * 128 + gg2 * 32 + j];

  float wk[EMB_N][4];
  float bb[4];
#pragma unroll
  for (int e = 0; e < EMB_N; ++e)
#pragma unroll
    for (int gg2 = 0; gg2 < 4; ++gg2) wk[e][gg2] = W[e * 128 + gg2 * 32 + j];
#pragma unroll
  for (int gg2 = 0; gg2 < 4; ++gg2) bb[gg2] = bias[gg2 * 32 + j];
  __syncthreads();

  float c = 0.0f, h = 0.0f;
  float4 h4[8];
#pragma unroll
  for (int q = 0; q < 8; ++q) h4[q] = make_float4(0.f, 0.f, 0.f, 0.f);

  for (int t = 0; t < T_N; ++t) {
    const int tokc = tokl[wrow][t];
    const float4* ev = reinterpret_cast<const float4*>(emb + (size_t)tokc * EMB_N);
    float4 e0 = ev[0], e1 = ev[1], e2 = ev[2], e3 = ev[3];
    const float em[16] = {e0.x,e0.y,e0.z,e0.w, e1.x,e1.y,e1.z,e1.w,
                          e2.x,e2.y,e2.z,e2.w, e3.x,e3.y,e3.z,e3.w};
    float a0 = bb[0], a1 = bb[1], a2 = bb[2], a3 = bb[3];
#pragma unroll
    for (int e = 0; e < EMB_N; ++e) {
      float x = em[e];
      a0 = fmaf(x, wk[e][0], a0); a1 = fmaf(x, wk[e][1], a1);
      a2 = fmaf(x, wk[e][2], a2); a3 = fmaf(x, wk[e][3], a3);
    }
#pragma unroll
    for (int q = 0; q < 8; ++q) {
      float hx = h4[q].x, hy = h4[q].y, hz = h4[q].z, hw = h4[q].w;
      a0 = fmaf(hx, wr[4*q+0][0], a0); a1 = fmaf(hx, wr[4*q+0][1], a1);
      a2 = fmaf(hx, wr[4*q+0][2], a2); a3 = fmaf(hx, wr[4*q+0][3], a3);
      a0 = fmaf(hy, wr[4*q+1][0], a0); a1 = fmaf(hy, wr[4*q+1][1], a1);
      a2 = fmaf(hy, wr[4*q+1][2], a2); a3 = fmaf(hy, wr[4*q+1][3], a3);
      a0 = fmaf(hz, wr[4*q+2][0], a0); a1 = fmaf(hz, wr[4*q+2][1], a1);
      a2 = fmaf(hz, wr[4*q+2][2], a2); a3 = fmaf(hz, wr[4*q+2][3], a3);
      a0 = fmaf(hw, wr[4*q+3][0], a0); a1 = fmaf(hw, wr[4*q+3][1], a1);
      a2 = fmaf(hw, wr[4*q+3][2], a2); a3 = fmaf(hw, wr[4*q+3][3], a3);
    }
    float ig = sigm(a0), fg = sigm(a1), gg = tanh_fast(a2), og = sigm(a3);
    float cn = fmaf(fg, c, ig * gg);
    float hn = og * tanh_fast(cn);
    if (tokc != 0) { h = hn; c = cn; }
    hbuf[wrow][j] = h;
    asm volatile("" ::: "memory");
#pragma unroll
    for (int q = 0; q < 8; ++q)
      h4[q] = reinterpret_cast<const float4*>(&hbuf[wrow][0])[q];
    asm volatile("" ::: "memory");
  }
  out[(size_t)row * HID_N + j] = h;
}

extern "C" void kernel_launch(void* const* d_in, const int* in_sizes, int n_in,
                              void* d_out, int out_size, void* d_ws, size_t ws_size,
                              hipStream_t stream) {
  const int*   tokens = (const int*)  d_in[0];
  const float* emb    = (const float*)d_in[1];
  const float* W      = (const float*)d_in[2];
  const float* rec    = (const float*)d_in[3];
  const float* bias   = (const float*)d_in[4];
  float* out = (float*)d_out;

  const size_t need = (size_t)VOCAB_N * 128 * sizeof(float);  // 25.6 MB
  if (ws_size >= need) {
    float* proj = (float*)d_ws;
    const long long total = (long long)VOCAB_N * 128;
    build_proj_mfma<<<(int)((total + 255) / 256), 256, 0, stream>>>(emb, W, bias, proj);
    lstm_mfma_kernel<<<B_N / 4, 64, 0, stream>>>(tokens, rec, proj, out);
  } else {
    lstm_scan_fallback<<<B_N / 8, 256, 0, stream>>>(tokens, rec, emb, W, bias, out);
  }
}

// Round 6
// 392.930 us; speedup vs baseline: 1.1157x; 1.1157x over previous
//
#include <hip/hip_runtime.h>
#include <cstdint>

#define VOCAB_N 50000
#define EMB_N   16
#define HID_N   32
#define B_N     4096
#define T_N     500
#define LOG2E     1.4426950408889634f
#define TWOLOG2E  2.8853900817779268f

typedef __attribute__((ext_vector_type(8))) short bf16x8;
typedef __attribute__((ext_vector_type(4))) float f32x4;
typedef __attribute__((ext_vector_type(4))) unsigned int u32x4;

__device__ __forceinline__ float frcp(float x) { return __builtin_amdgcn_rcpf(x); }

// split: x = hi(bf16) + lo(bf16) + O(2^-24 x); packed u32: [15:0]=hi, [31:16]=lo
__device__ __forceinline__ unsigned bf16_split_pack(float x) {
  unsigned u  = __builtin_bit_cast(unsigned, x);
  float hif = __builtin_bit_cast(float, u & 0xFFFF0000u);
  float r   = x - hif;                       // exact
  unsigned lo = __builtin_bit_cast(unsigned, r) >> 16;
  return (u >> 16) | (lo << 16);
}
__device__ __forceinline__ float unpack_h(unsigned p) {
  float hi = __builtin_bit_cast(float, p << 16);
  float lo = __builtin_bit_cast(float, p & 0xFFFF0000u);
  return hi + lo;
}

// ---------------------------------------------------------------------------
// proj[v*128 + c*8 + par*4 + n2] = LOG2E * (bias[col] + emb[v]·W[:,col]),
//   col = (2*n2+par)*16 + c     (c=0..15, par=0..1, n2=0..3)
// Wave w reads float4 at (v*128 + c*8 + w*4): components n2=q -> N-tile 2q+w.
// ---------------------------------------------------------------------------
__global__ void build_proj_ns(const float* __restrict__ emb,
                              const float* __restrict__ W,
                              const float* __restrict__ bias,
                              float* __restrict__ proj) {
  __shared__ float Wl[EMB_N * 128];
  __shared__ float bl[128];
  const int tid = threadIdx.x;
  for (int i = tid; i < EMB_N * 128 / 4; i += 256)
    reinterpret_cast<float4*>(Wl)[i] = reinterpret_cast<const float4*>(W)[i];
  if (tid < 32)
    reinterpret_cast<float4*>(bl)[tid] = reinterpret_cast<const float4*>(bias)[tid];
  __syncthreads();

  const long long gid = (long long)blockIdx.x * 256 + tid;
  if (gid >= (long long)VOCAB_N * 128) return;
  const int v = (int)(gid >> 7);
  const int q = (int)(gid & 127);
  const int c  = q >> 3;
  const int par = (q >> 2) & 1;
  const int n2 = q & 3;
  const int col = (2 * n2 + par) * 16 + c;

  const float4* ev = reinterpret_cast<const float4*>(emb + (size_t)v * EMB_N);
  float4 e0 = ev[0], e1 = ev[1], e2 = ev[2], e3 = ev[3];
  const float em[16] = {e0.x,e0.y,e0.z,e0.w, e1.x,e1.y,e1.z,e1.w,
                        e2.x,e2.y,e2.z,e2.w, e3.x,e3.y,e3.z,e3.w};
  float a = bl[col];
#pragma unroll
  for (int e = 0; e < EMB_N; ++e) a = fmaf(em[e], Wl[e * 128 + col], a);
  proj[gid] = a * LOG2E;
}

// ---------------------------------------------------------------------------
// Scan: block = 16 batch rows, 2 waves (N-split). Wave w computes N-tiles
// {w,2+w,4+w,6+w} -> unit = 16w + (l&15), all 4 gates lane-local.
// C-layout (m89, HW-verified R5): row=(l>>4)*4+reg, col=l&15.
// A-frag: lane holds A[row=l&15][k=(l>>4)*8+j]  (verified R5).
// h exchanged as packed (hi|lo) u32 via double-buffered LDS, 1 raw barrier.
// ---------------------------------------------------------------------------
#define GATE(R, TOK, CC, HH)                                                  \
  {                                                                           \
    float zi = z0[R], zf = z1[R], zg = z2[R], zo = z3[R];                     \
    float gi = frcp(1.0f + exp2f(-zi));                                       \
    float gf = frcp(1.0f + exp2f(-zf));                                       \
    float gg = fmaf(-2.0f, frcp(1.0f + exp2f(zg + zg)), 1.0f);                \
    float go = frcp(1.0f + exp2f(-zo));                                       \
    float cn = fmaf(gf, CC, gi * gg);                                         \
    float tc = fmaf(-2.0f, frcp(1.0f + exp2f(cn * TWOLOG2E)), 1.0f);          \
    float hn = go * tc;                                                       \
    bool m = (TOK) != 0;                                                      \
    CC = m ? cn : CC;                                                         \
    unsigned hp_ = bf16_split_pack(hn);                                       \
    HH = m ? hp_ : HH;                                                        \
    hl[pp ^ 1][rb + (R)][unit] = HH;                                          \
  }

#define BODY(TM, TP, X0, X1, X2, X3, TT4)                                     \
  {                                                                           \
    const unsigned* hrow = &hl[pp][c16][g8];                                  \
    u32x4 wa = *reinterpret_cast<const u32x4*>(hrow);                         \
    u32x4 wb = *reinterpret_cast<const u32x4*>(hrow + 4);                     \
    u32x4 ahp, alp;                                                           \
    ahp[0] = __builtin_amdgcn_perm(wa[1], wa[0], 0x05040100u);                \
    alp[0] = __builtin_amdgcn_perm(wa[1], wa[0], 0x07060302u);                \
    ahp[1] = __builtin_amdgcn_perm(wa[3], wa[2], 0x05040100u);                \
    alp[1] = __builtin_amdgcn_perm(wa[3], wa[2], 0x07060302u);                \
    ahp[2] = __builtin_amdgcn_perm(wb[1], wb[0], 0x05040100u);                \
    alp[2] = __builtin_amdgcn_perm(wb[1], wb[0], 0x07060302u);                \
    ahp[3] = __builtin_amdgcn_perm(wb[3], wb[2], 0x05040100u);                \
    alp[3] = __builtin_amdgcn_perm(wb[3], wb[2], 0x07060302u);                \
    bf16x8 Ah = __builtin_bit_cast(bf16x8, ahp);                              \
    bf16x8 Al = __builtin_bit_cast(bf16x8, alp);                              \
    f32x4 z0 = {(X0).x, (X1).x, (X2).x, (X3).x};                              \
    f32x4 z1 = {(X0).y, (X1).y, (X2).y, (X3).y};                              \
    f32x4 z2 = {(X0).z, (X1).z, (X2).z, (X3).z};                              \
    f32x4 z3 = {(X0).w, (X1).w, (X2).w, (X3).w};                              \
    /* prefetch x_proj for t+2 (vmcnt stays outstanding across the barrier) */\
    (X0) = *reinterpret_cast<const float4*>(projw + (size_t)(TP).x * 128);    \
    (X1) = *reinterpret_cast<const float4*>(projw + (size_t)(TP).y * 128);    \
    (X2) = *reinterpret_cast<const float4*>(projw + (size_t)(TP).z * 128);    \
    (X3) = *reinterpret_cast<const float4*>(projw + (size_t)(TP).w * 128);    \
    z0 = __builtin_amdgcn_mfma_f32_16x16x32_bf16(Ah, Bh0, z0, 0, 0, 0);       \
    z1 = __builtin_amdgcn_mfma_f32_16x16x32_bf16(Ah, Bh1, z1, 0, 0, 0);       \
    z2 = __builtin_amdgcn_mfma_f32_16x16x32_bf16(Ah, Bh2, z2, 0, 0, 0);       \
    z3 = __builtin_amdgcn_mfma_f32_16x16x32_bf16(Ah, Bh3, z3, 0, 0, 0);       \
    z0 = __builtin_amdgcn_mfma_f32_16x16x32_bf16(Al, Bh0, z0, 0, 0, 0);       \
    z1 = __builtin_amdgcn_mfma_f32_16x16x32_bf16(Al, Bh1, z1, 0, 0, 0);       \
    z2 = __builtin_amdgcn_mfma_f32_16x16x32_bf16(Al, Bh2, z2, 0, 0, 0);       \
    z3 = __builtin_amdgcn_mfma_f32_16x16x32_bf16(Al, Bh3, z3, 0, 0, 0);       \
    z0 = __builtin_amdgcn_mfma_f32_16x16x32_bf16(Ah, Bl0, z0, 0, 0, 0);       \
    z1 = __builtin_amdgcn_mfma_f32_16x16x32_bf16(Ah, Bl1, z1, 0, 0, 0);       \
    z2 = __builtin_amdgcn_mfma_f32_16x16x32_bf16(Ah, Bl2, z2, 0, 0, 0);       \
    z3 = __builtin_amdgcn_mfma_f32_16x16x32_bf16(Ah, Bl3, z3, 0, 0, 0);       \
    /* token prefetch for t+4 */                                              \
    int4 tnew = make_int4(tokl[rb + 0][TT4], tokl[rb + 1][TT4],               \
                          tokl[rb + 2][TT4], tokl[rb + 3][TT4]);              \
    GATE(0, (TM).x, c0, hr0)                                                  \
    GATE(1, (TM).y, c1, hr1)                                                  \
    GATE(2, (TM).z, c2, hr2)                                                  \
    GATE(3, (TM).w, c3, hr3)                                                  \
    asm volatile("s_waitcnt lgkmcnt(0)" ::: "memory");                        \
    __builtin_amdgcn_s_barrier();                                             \
    asm volatile("" ::: "memory");                                            \
    __builtin_amdgcn_sched_barrier(0);                                        \
    pp ^= 1;                                                                  \
    (TM) = (TP); (TP) = tnew;                                                 \
  }

__global__ __launch_bounds__(128, 1)
void lstm_mfma_ns(const int*   __restrict__ tokens,
                  const float* __restrict__ rec_kernel,  // [32][128] f32
                  const float* __restrict__ proj,        // scaled, permuted
                  float*       __restrict__ out) {
  __shared__ int      tokl[16][512];       // 32 KiB
  __shared__ unsigned hl[2][16][36];       // packed h, dbuf, stride 36 u32

  const int tid = threadIdx.x;
  const int wv  = tid >> 6;                // wave 0/1 -> units 0-15 / 16-31
  const int l   = tid & 63;
  const int c16 = l & 15;
  const int g   = l >> 4;
  const int g8  = g * 8;
  const int rb  = g * 4;                   // C-layout row base for this lane
  const int unit = wv * 16 + c16;

  // ---- stage tokens: 16 rows x 500 ints ----
  {
    const int4* src = reinterpret_cast<const int4*>(tokens + (size_t)blockIdx.x * 16 * T_N);
    for (int i = tid; i < 16 * T_N / 4; i += 128) {
      int4 v4 = src[i];
      int gi = 4 * i;
      int r  = gi / T_N;                   // 500 % 4 == 0: no straddle
      int cc = gi - r * T_N;
      *reinterpret_cast<int4*>(&tokl[r][cc]) = v4;
    }
    for (int i = tid; i < 16 * 12; i += 128) {
      int r = i / 12; tokl[r][T_N + (i % 12)] = 0;
    }
  }

  // ---- zero h (buffer 0), owner lanes ----
  hl[0][rb + 0][unit] = 0; hl[0][rb + 1][unit] = 0;
  hl[0][rb + 2][unit] = 0; hl[0][rb + 3][unit] = 0;

  // ---- B-frags of R*LOG2E for this wave's N-tiles {wv, 2+wv, 4+wv, 6+wv} ----
  bf16x8 Bh0, Bh1, Bh2, Bh3, Bl0, Bl1, Bl2, Bl3;
#define BUILD_B(Q, BH, BL)                                                    \
  {                                                                           \
    _Pragma("unroll")                                                         \
    for (int j = 0; j < 8; ++j) {                                             \
      float x = rec_kernel[(g8 + j) * 128 + (2 * (Q) + wv) * 16 + c16] * LOG2E;\
      unsigned s_ = bf16_split_pack(x);                                       \
      (BH)[j] = (short)s_; (BL)[j] = (short)(s_ >> 16);                       \
    }                                                                         \
  }
  BUILD_B(0, Bh0, Bl0) BUILD_B(1, Bh1, Bl1)
  BUILD_B(2, Bh2, Bl2) BUILD_B(3, Bh3, Bl3)
#undef BUILD_B

  __syncthreads();

  float    c0 = 0.f, c1 = 0.f, c2 = 0.f, c3 = 0.f;
  unsigned hr0 = 0, hr1 = 0, hr2 = 0, hr3 = 0;
  int pp = 0;

  // ---- token + xp pipelines (2 steps deep per slot) ----
  int4 tmA = make_int4(tokl[rb+0][0], tokl[rb+1][0], tokl[rb+2][0], tokl[rb+3][0]);
  int4 tmB = make_int4(tokl[rb+0][1], tokl[rb+1][1], tokl[rb+2][1], tokl[rb+3][1]);
  int4 tpA = make_int4(tokl[rb+0][2], tokl[rb+1][2], tokl[rb+2][2], tokl[rb+3][2]);
  int4 tpB = make_int4(tokl[rb+0][3], tokl[rb+1][3], tokl[rb+2][3], tokl[rb+3][3]);

  const float* projw = proj + c16 * 8 + wv * 4;
  float4 xA0 = *reinterpret_cast<const float4*>(projw + (size_t)tmA.x * 128);
  float4 xA1 = *reinterpret_cast<const float4*>(projw + (size_t)tmA.y * 128);
  float4 xA2 = *reinterpret_cast<const float4*>(projw + (size_t)tmA.z * 128);
  float4 xA3 = *reinterpret_cast<const float4*>(projw + (size_t)tmA.w * 128);
  float4 xB0 = *reinterpret_cast<const float4*>(projw + (size_t)tmB.x * 128);
  float4 xB1 = *reinterpret_cast<const float4*>(projw + (size_t)tmB.y * 128);
  float4 xB2 = *reinterpret_cast<const float4*>(projw + (size_t)tmB.z * 128);
  float4 xB3 = *reinterpret_cast<const float4*>(projw + (size_t)tmB.w * 128);

#pragma unroll 1
  for (int t = 0; t < T_N; t += 2) {
    BODY(tmA, tpA, xA0, xA1, xA2, xA3, t + 4);
    BODY(tmB, tpB, xB0, xB1, xB2, xB3, t + 5);
  }

  const size_t obase = (size_t)blockIdx.x * 16 + rb;
  out[(obase + 0) * HID_N + unit] = unpack_h(hr0);
  out[(obase + 1) * HID_N + unit] = unpack_h(hr1);
  out[(obase + 2) * HID_N + unit] = unpack_h(hr2);
  out[(obase + 3) * HID_N + unit] = unpack_h(hr3);
}

// ---------------------------------------------------------------------------
// Fallback (no workspace): proven round-1 kernel.
// ---------------------------------------------------------------------------
__device__ __forceinline__ float sigm_fb(float x) {
  return frcp(1.0f + exp2f(x * -1.4426950408889634f));
}
__device__ __forceinline__ float tanh_fb(float x) {
  float e = exp2f(x * 2.8853900817779268f);
  return fmaf(-2.0f, frcp(e + 1.0f), 1.0f);
}

__global__ __launch_bounds__(256, 2)
void lstm_scan_fallback(const int*   __restrict__ tokens,
                        const float* __restrict__ rec_kernel,
                        const float* __restrict__ emb,
                        const float* __restrict__ W,
                        const float* __restrict__ bias,
                        float*       __restrict__ out) {
  __shared__ int   tokl[8][T_N];
  __shared__ float hbuf[8][HID_N];

  const int tid  = threadIdx.x;
  const int wv   = tid >> 6;
  const int lane = tid & 63;
  const int half = lane >> 5;
  const int j    = lane & 31;
  const int wrow = wv * 2 + half;
  const int row  = blockIdx.x * 8 + wrow;

  {
    const int4* src = reinterpret_cast<const int4*>(tokens + (size_t)blockIdx.x * 8 * T_N);
    int4* dst = reinterpret_cast<int4*>(&tokl[0][0]);
    for (int i = tid; i < 8 * T_N / 4; i += 256) dst[i] = src[i];
  }

  float wr[HID_N][4];
#pragma unroll
  for (int k = 0; k < HID_N; ++k)
#pragma unroll
    for (int gg2 = 0; gg2 < 4; ++gg2) wr[k][gg2] = rec_kernel[k * 128 + gg2 * 32 + j];

  float wk[EMB_N][4];
  float bb[4];
#pragma unroll
  for (int e = 0; e < EMB_N; ++e)
#pragma unroll
    for (int gg2 = 0; gg2 < 4; ++gg2) wk[e][gg2] = W[e * 128 + gg2 * 32 + j];
#pragma unroll
  for (int gg2 = 0; gg2 < 4; ++gg2) bb[gg2] = bias[gg2 * 32 + j];
  __syncthreads();

  float c = 0.0f, h = 0.0f;
  float4 h4[8];
#pragma unroll
  for (int q = 0; q < 8; ++q) h4[q] = make_float4(0.f, 0.f, 0.f, 0.f);

  for (int t = 0; t < T_N; ++t) {
    const int tokc = tokl[wrow][t];
    const float4* ev = reinterpret_cast<const float4*>(emb + (size_t)tokc * EMB_N);
    float4 e0 = ev[0], e1 = ev[1], e2 = ev[2], e3 = ev[3];
    const float em[16] = {e0.x,e0.y,e0.z,e0.w, e1.x,e1.y,e1.z,e1.w,
                          e2.x,e2.y,e2.z,e2.w, e3.x,e3.y,e3.z,e3.w};
    float a0 = bb[0], a1 = bb[1], a2 = bb[2], a3 = bb[3];
#pragma unroll
    for (int e = 0; e < EMB_N; ++e) {
      float x = em[e];
      a0 = fmaf(x, wk[e][0], a0); a1 = fmaf(x, wk[e][1], a1);
      a2 = fmaf(x, wk[e][2], a2); a3 = fmaf(x, wk[e][3], a3);
    }
#pragma unroll
    for (int q = 0; q < 8; ++q) {
      float hx = h4[q].x, hy = h4[q].y, hz = h4[q].z, hw = h4[q].w;
      a0 = fmaf(hx, wr[4*q+0][0], a0); a1 = fmaf(hx, wr[4*q+0][1], a1);
      a2 = fmaf(hx, wr[4*q+0][2], a2); a3 = fmaf(hx, wr[4*q+0][3], a3);
      a0 = fmaf(hy, wr[4*q+1][0], a0); a1 = fmaf(hy, wr[4*q+1][1], a1);
      a2 = fmaf(hy, wr[4*q+1][2], a2); a3 = fmaf(hy, wr[4*q+1][3], a3);
      a0 = fmaf(hz, wr[4*q+2][0], a0); a1 = fmaf(hz, wr[4*q+2][1], a1);
      a2 = fmaf(hz, wr[4*q+2][2], a2); a3 = fmaf(hz, wr[4*q+2][3], a3);
      a0 = fmaf(hw, wr[4*q+3][0], a0); a1 = fmaf(hw, wr[4*q+3][1], a1);
      a2 = fmaf(hw, wr[4*q+3][2], a2); a3 = fmaf(hw, wr[4*q+3][3], a3);
    }
    float ig = sigm_fb(a0), fg = sigm_fb(a1), gg = tanh_fb(a2), og = sigm_fb(a3);
    float cn = fmaf(fg, c, ig * gg);
    float hn = og * tanh_fb(cn);
    if (tokc != 0) { h = hn; c = cn; }
    hbuf[wrow][j] = h;
    asm volatile("" ::: "memory");
#pragma unroll
    for (int q = 0; q < 8; ++q)
      h4[q] = reinterpret_cast<const float4*>(&hbuf[wrow][0])[q];
    asm volatile("" ::: "memory");
  }
  out[(size_t)row * HID_N + j] = h;
}

extern "C" void kernel_launch(void* const* d_in, const int* in_sizes, int n_in,
                              void* d_out, int out_size, void* d_ws, size_t ws_size,
                              hipStream_t stream) {
  const int*   tokens = (const int*)  d_in[0];
  const float* emb    = (const float*)d_in[1];
  const float* W      = (const float*)d_in[2];
  const float* rec    = (const float*)d_in[3];
  const float* bias   = (const float*)d_in[4];
  float* out = (float*)d_out;

  const size_t need = (size_t)VOCAB_N * 128 * sizeof(float);  // 25.6 MB
  if (ws_size >= need) {
    float* proj = (float*)d_ws;
    const long long total = (long long)VOCAB_N * 128;
    build_proj_ns<<<(int)((total + 255) / 256), 256, 0, stream>>>(emb, W, bias, proj);
    lstm_mfma_ns<<<B_N / 16, 128, 0, stream>>>(tokens, rec, proj, out);
  } else {
    lstm_scan_fallback<<<B_N / 8, 256, 0, stream>>>(tokens, rec, emb, W, bias, out);
  }
}